// Round 5
// baseline (246.823 us; speedup 1.0000x reference)
//
#include <hip/hip_runtime.h>
#include <hip/hip_bf16.h>

// Problem constants: B=64, S=512, H=768, L=9
#define NB 64
#define NS 512
#define NH 768
#define NL 9
#define NROWS (NB*NS)          // 32768
#define EMN (NROWS*NL)         // 294912

// per-batch LDS strides (padded off %32==0 to avoid 4-way batch bank aliasing)
#define VST  4617              // floats per batch for s_v   (>= 512*9=4608; 9 pad slots)
#define BPST 4616              // bytes  per batch for s_bp  (>= 4608)

__device__ __forceinline__ float readlane_f(float v, int l) {
    return __int_as_float(__builtin_amdgcn_readlane(__float_as_int(v), l));
}
__device__ __forceinline__ unsigned long long readlane_u64(unsigned long long v, int l) {
    unsigned int lo = (unsigned int)__builtin_amdgcn_readlane((int)(unsigned int)(v & 0xffffffffULL), l);
    unsigned int hi = (unsigned int)__builtin_amdgcn_readlane((int)(unsigned int)(v >> 32), l);
    return ((unsigned long long)hi << 32) | (unsigned long long)lo;
}
// DPP add: x += dpp_move(x, CTRL); out-of-bound source lanes contribute 0.
template <int CTRL>
__device__ __forceinline__ float dpp_add(float x) {
    int t = __builtin_amdgcn_update_dpp(0, __float_as_int(x), CTRL, 0xf, 0xf, false);
    return x + __int_as_float(t);
}
// Canonical gfx9 wave64 sum; total lands in lane 63. Pure VALU (no LDS pipe).
__device__ __forceinline__ float wave_sum_to63(float x) {
    x = dpp_add<0x111>(x);  // row_shr:1
    x = dpp_add<0x112>(x);  // row_shr:2
    x = dpp_add<0x114>(x);  // row_shr:4
    x = dpp_add<0x118>(x);  // row_shr:8  (lane15 of each row = row sum)
    x = dpp_add<0x142>(x);  // row_bcast:15
    x = dpp_add<0x143>(x);  // row_bcast:31 -> lane63 = wave sum
    return x;
}
// ds_swizzle row-broadcast: every lane receives the value held by lane I of its
// own 16-lane row. BitMode offset = (xor<<10) | (or<<5) | and -> (I<<5) | 0x10.
template <int I>
__device__ __forceinline__ float rowbc(float x) {
    return __int_as_float(__builtin_amdgcn_ds_swizzle(__float_as_int(x), (I << 5) | 0x10));
}

// ---------------- Kernel A: emissions GEMM (K split across waves) ----------------
// (R0/R2-proven version; three structurally different variants all timed the same,
//  i.e. this kernel is at its memory/latency floor — leave it alone.)
__global__ __launch_bounds__(256) void k_gemm(const float* __restrict__ hidden,
                                              const float* __restrict__ W,
                                              const float* __restrict__ bias,
                                              float* __restrict__ em,
                                              float* __restrict__ out) {
    __shared__ float s_part[4][4][NL];   // [wave][row][j]
    int tid = threadIdx.x;
    int lane = tid & 63;
    int w = tid >> 6;
    int bx = blockIdx.x;
    if (bx == 0 && tid == 0) { out[0] = 0.f; out[1] = 0.f; }

    int kbase = 192 * w + lane;          // + 64c, c=0..2
    float Wv[3][NL];
#pragma unroll
    for (int c = 0; c < 3; c++) {
        const float* wp = W + (size_t)(kbase + 64 * c) * NL;
#pragma unroll
        for (int j = 0; j < NL; j++) Wv[c][j] = wp[j];
    }

#pragma unroll
    for (int r = 0; r < 4; r++) {
        int row = 4 * bx + r;
        const float* hp = hidden + (size_t)row * NH + kbase;
        float h0 = hp[0], h1 = hp[64], h2 = hp[128];
        float acc[NL];
#pragma unroll
        for (int j = 0; j < NL; j++) {
            acc[j] = fmaf(h0, Wv[0][j], fmaf(h1, Wv[1][j], h2 * Wv[2][j]));
        }
#pragma unroll
        for (int j = 0; j < NL; j++) acc[j] = wave_sum_to63(acc[j]);
        if (lane == 63) {
#pragma unroll
            for (int j = 0; j < NL; j++) s_part[w][r][j] = acc[j];
        }
    }
    __syncthreads();
    if (tid < 36) {
        int r = tid / NL, j = tid % NL;
        float v = (s_part[0][r][j] + s_part[1][r][j]) +
                  (s_part[2][r][j] + s_part[3][r][j]) + bias[j];
        em[(size_t)(4 * bx + r) * NL + j] = v;
    }
}

// ---------------- Kernel B: DP + finalize (merged fwd+viterbi chains) ----------------
// 16 blocks. wave0 runs BOTH the forward chain and the Viterbi chain for 4 batches
// (one per 16-lane row): the two chains are independent, so their 9-swizzle LDS
// round-trips share one latency window per step instead of each wave stalling
// alone on a different CU (R4 evidence: VALUBusy 2-5%, per-step ~176cy vs ~50cy
// compute = latency-exposed). wave1 = gold-path numerator. Then all 256 threads:
// backpointers, backtrack, finalize. All fp op trees verbatim from the R2-proven
// kernel -> outputs bit-identical.
__global__ __launch_bounds__(256) void k_dp(const float* __restrict__ em,
                                            const int* __restrict__ label,
                                            const int* __restrict__ mask,
                                            const float* __restrict__ startT,
                                            const float* __restrict__ endT,
                                            const float* __restrict__ trans,
                                            float* __restrict__ out) {
    __shared__ float s_T[NL * NL];
    __shared__ int s_mki[4][NS];                 // masks for the block's 4 batches
    __shared__ float s_v[4 * VST];               // viterbi value history (padded stride)
    __shared__ unsigned char s_bp[4 * BPST];     // backpointers
    __shared__ unsigned char s_path[4 * NS];     // decoded paths

    int bx = blockIdx.x;
    int tid = threadIdx.x;
    int lane = tid & 63;
    int b0 = bx * 4;

    if (tid < NL * NL) s_T[tid] = trans[tid];
    for (int q = tid; q < 4 * NS / 4; q += 256)
        ((int4*)s_mki)[q] = ((const int4*)(mask + b0 * NS))[q];
    __syncthreads();

    if (tid < 64) {
        // ---- merged forward + viterbi chains, 4 batches (one per 16-lane row) ----
        int bb = lane >> 4;
        int jcol = lane & 15;
        int jcol9 = jcol < NL ? jcol : NL - 1;
        const float* gp = em + (size_t)(b0 + bb) * (NS * NL) + jcol9;
        // forward tables (exp) + viterbi tables (raw), same column jcol9
        float Mc0 = __expf(s_T[0 * NL + jcol9]), Tc0 = s_T[0 * NL + jcol9];
        float Mc1 = __expf(s_T[1 * NL + jcol9]), Tc1 = s_T[1 * NL + jcol9];
        float Mc2 = __expf(s_T[2 * NL + jcol9]), Tc2 = s_T[2 * NL + jcol9];
        float Mc3 = __expf(s_T[3 * NL + jcol9]), Tc3 = s_T[3 * NL + jcol9];
        float Mc4 = __expf(s_T[4 * NL + jcol9]), Tc4 = s_T[4 * NL + jcol9];
        float Mc5 = __expf(s_T[5 * NL + jcol9]), Tc5 = s_T[5 * NL + jcol9];
        float Mc6 = __expf(s_T[6 * NL + jcol9]), Tc6 = s_T[6 * NL + jcol9];
        float Mc7 = __expf(s_T[7 * NL + jcol9]), Tc7 = s_T[7 * NL + jcol9];
        float Mc8 = __expf(s_T[8 * NL + jcol9]), Tc8 = s_T[8 * NL + jcol9];
        float st0 = startT[jcol9] + gp[0];
        float a = __expf(st0);       // forward state (linear domain)
        float v = st0;               // viterbi state
        int eacc = 0;
        int svbase = bb * VST + jcol;
        s_v[svbase] = v;             // t = 0 (lanes 9..15 hit pad-overwritten slots)

#define SWZ9(SRC_, A0,A1,A2,A3,A4,A5,A6,A7,A8) \
    float A0 = rowbc<0>(SRC_), A1 = rowbc<1>(SRC_), A2 = rowbc<2>(SRC_); \
    float A3 = rowbc<3>(SRC_), A4 = rowbc<4>(SRC_), A5 = rowbc<5>(SRC_); \
    float A6 = rowbc<6>(SRC_), A7 = rowbc<7>(SRC_), A8 = rowbc<8>(SRC_)

// One merged step: issue all 18 swizzles first (one shared latency window),
// then the viterbi tree (bit-exact R2 op order), then the forward tree (ditto).
#define STEP(EV_, EF_, KC_, T_) do { \
    SWZ9(v, _w0,_w1,_w2,_w3,_w4,_w5,_w6,_w7,_w8); \
    SWZ9(a, _q0,_q1,_q2,_q3,_q4,_q5,_q6,_q7,_q8); \
    float _m0=_w0+Tc0,_m1=_w1+Tc1,_m2=_w2+Tc2,_m3=_w3+Tc3,_m4=_w4+Tc4, \
          _m5=_w5+Tc5,_m6=_w6+Tc6,_m7=_w7+Tc7,_m8=_w8+Tc8; \
    float _Ma=fmaxf(fmaxf(_m0,_m1),_m2); \
    float _Mb=fmaxf(fmaxf(_m3,_m4),_m5); \
    float _Mc=fmaxf(fmaxf(_m6,_m7),_m8); \
    v = fmaxf(fmaxf(_Ma,_Mb),_Mc) + (EV_); \
    s_v[svbase + (T_) * NL] = v; \
    float _p0=_q0*Mc0,_p1=_q1*Mc1,_p2=_q2*Mc2,_p3=_q3*Mc3,_p4=_q4*Mc4, \
          _p5=_q5*Mc5,_p6=_q6*Mc6,_p7=_q7*Mc7,_p8=_q8*Mc8; \
    float _s=(((_p0+_p1)+(_p2+_p3))+((_p4+_p5)+(_p6+_p7)))+_p8; \
    float _an=(EF_)*_s; \
    a = ((KC_) > 0) ? _an : a; \
} while (0)

#define FREN() do { \
    SWZ9(a, _c0,_c1,_c2,_c3,_c4,_c5,_c6,_c7,_c8); \
    float _cc=(((_c0+_c1)+(_c2+_c3))+((_c4+_c5)+(_c6+_c7)))+_c8; \
    int _ex=((__float_as_int(_cc)>>23)&255)-127; \
    a=ldexpf(a,-_ex); eacc+=_ex; \
} while (0)

        float ef8[8]; float ev8[8]; int k8[8];
#pragma unroll
        for (int p = 0; p < 8; p++) {
            float raw = gp[(1 + p) * NL];
            ev8[p] = raw;
            ef8[p] = __expf(raw);
            k8[p] = s_mki[bb][1 + p];
        }
        for (int t0 = 1; t0 <= NS - 15; t0 += 8) {   // t0 = 1,9,...,497
#pragma unroll
            for (int p = 0; p < 8; p++) {
                int t = t0 + p;
                float ecv = ev8[p]; float ecf = ef8[p]; int kc = k8[p];
                int tn = t + 8; tn = tn > NS - 1 ? NS - 1 : tn;
                float raw = gp[tn * NL];             // prefetch 8 ahead
                ev8[p] = raw;
                ef8[p] = __expf(raw);
                k8[p] = s_mki[bb][tn];
                STEP(ecv, ecf, kc, t);
                if (p == 7) FREN();                  // t = 8,16,...,504
            }
        }
#pragma unroll
        for (int p = 0; p < 7; p++) STEP(ev8[p], ef8[p], k8[p], 505 + p);
#undef STEP
#undef FREN
        // ---- forward epilogue: logZ ----
        float z = a * __expf(endT[jcol9]);
        SWZ9(z, zc0,zc1,zc2,zc3,zc4,zc5,zc6,zc7,zc8);
        float c = (((zc0 + zc1) + (zc2 + zc3)) + ((zc4 + zc5) + (zc6 + zc7))) + zc8;
        if (jcol == 0) {
            float lz = (float)eacc * 0.6931471805599453f + __logf(c);
            atomicAdd(out, lz * (1.0f / (float)NB));
        }
#undef SWZ9
    } else if (tid < 128) {
        // ---- numerator (gold path score), one 16-lane group per batch ----
        int g = lane >> 4;
        int ll = lane & 15;
        int b = b0 + g;
        const int* lb = label + b * NS;
        const float* ge = em + (size_t)b * NS * NL;
        int h = 0, sl = 0;
        for (int cch = 0; cch < 4; cch++) {
            int la8[8]; int mk8[8];
#pragma unroll
            for (int r = 0; r < 8; r++) {
                int t = ll * 32 + cch * 8 + r;
                la8[r] = lb[t];
                int m = s_mki[g][t];
                if (t == 0) m = 1;
                mk8[r] = m;
            }
#pragma unroll
            for (int r = 0; r < 8; r++) if (mk8[r] > 0) { h = 1; sl = la8[r]; }
        }
#pragma unroll
        for (int d = 1; d < 16; d <<= 1) {
            int ho = __shfl_up(h, d, 16);
            int so = __shfl_up(sl, d, 16);
            if (!h) { h = ho; sl = so; }
        }
        int lg = __shfl(sl, 15, 16);
        int incoming = __shfl_up(sl, 1, 16);
        int labz = lb[0];
        int prevr = (ll == 0) ? labz : incoming;
        float sc = 0.f;
        for (int cch = 0; cch < 4; cch++) {
            int la8[8]; int mk8[8]; float ev8[8];
#pragma unroll
            for (int r = 0; r < 8; r++) {
                int t = ll * 32 + cch * 8 + r;
                la8[r] = lb[t];
                int m = s_mki[g][t];
                if (t == 0) m = 1;
                mk8[r] = m;
            }
#pragma unroll
            for (int r = 0; r < 8; r++) {
                int t = ll * 32 + cch * 8 + r;
                ev8[r] = ge[t * NL + la8[r]];
            }
#pragma unroll
            for (int r = 0; r < 8; r++) {
                int t = ll * 32 + cch * 8 + r;
                if (t > 0) {
                    float s = s_T[prevr * NL + la8[r]] + ev8[r];
                    sc += s * (float)mk8[r];
                }
                if (mk8[r] > 0) prevr = la8[r];
            }
        }
        if (ll == 0) sc += startT[labz] + ge[labz] + endT[lg];
#pragma unroll
        for (int d = 1; d < 16; d <<= 1) sc += __shfl_xor(sc, d, 16);
        if (ll == 0) atomicAdd(out, -sc * (1.0f / (float)NB));
    }
    __syncthreads();
    // ---- phase 2: backpointers, parallel over (batch, t); exact ref op order ----
    for (int it = 0; it < 8; it++) {
        int item = tid + it * 256;
        int bb = item >> 9;
        int t = item & (NS - 1);
        if (t > 0) {
            const float* vpp = s_v + bb * VST + (t - 1) * NL;
            const float* ge = em + (size_t)(b0 + bb) * (NS * NL) + t * NL;
            float vp[NL], emt[NL];
#pragma unroll
            for (int i = 0; i < NL; i++) vp[i] = vpp[i];
#pragma unroll
            for (int j = 0; j < NL; j++) emt[j] = ge[j];
#pragma unroll
            for (int j = 0; j < NL; j++) {
                float e = emt[j];
                float val[NL];
#pragma unroll
                for (int i = 0; i < NL; i++) val[i] = (vp[i] + s_T[i * NL + j]) + e;
                bool c01 = val[0] >= val[1]; float m01 = c01 ? val[0] : val[1]; int i01 = c01 ? 0 : 1;
                bool c23 = val[2] >= val[3]; float m23 = c23 ? val[2] : val[3]; int i23 = c23 ? 2 : 3;
                bool c45 = val[4] >= val[5]; float m45 = c45 ? val[4] : val[5]; int i45 = c45 ? 4 : 5;
                bool c67 = val[6] >= val[7]; float m67 = c67 ? val[6] : val[7]; int i67 = c67 ? 6 : 7;
                bool ca = m01 >= m23; float ma = ca ? m01 : m23; int ia = ca ? i01 : i23;
                bool cb = m45 >= m67; float mb = cb ? m45 : m67; int ib = cb ? i45 : i67;
                bool cc = ma >= mb;  float mc = cc ? ma : mb;  int ic = cc ? ia : ib;
                bool cd = mc >= val[8]; int bi = cd ? ic : 8;
                s_bp[bb * BPST + t * NL + j] = (unsigned char)bi;
            }
        }
    }
    __syncthreads();
    // ---- phase 3: last tag + map-composition backtrack (wave w -> batch w) ----
    {
        int w = tid >> 6;
        const float* sv = s_v + w * VST;
        const unsigned char* bpp = s_bp + w * BPST;
        unsigned char* pth = s_path + w * NS;
        float bb2 = sv[(NS - 1) * NL + 0] + endT[0]; int lt = 0;
#pragma unroll
        for (int jj = 1; jj < NL; jj++) {
            float fj = sv[(NS - 1) * NL + jj] + endT[jj];
            if (fj > bb2) { bb2 = fj; lt = jj; }
        }
        unsigned long long G[8];
#pragma unroll
        for (int r = 0; r < 8; r++) {
            int t0 = (lane * 8 + r) * NL;
            unsigned long long g = 0;
            if (lane == 0 && r == 0) {
                g = 0x876543210ULL;   // t=0 identity (bp[0] unused)
            } else {
#pragma unroll
                for (int x = 0; x < NL; x++) g |= (unsigned long long)bpp[t0 + x] << (4 * x);
            }
            G[r] = g;
        }
        unsigned long long A = 0x876543210ULL;
#pragma unroll
        for (int r = 7; r >= 0; r--) {
            unsigned long long An = 0;
#pragma unroll
            for (int x = 0; x < NL; x++) {
                int ax = (int)((A >> (4 * x)) & 15ULL);
                int gvv = (int)((G[r] >> (4 * ax)) & 15ULL);
                An |= (unsigned long long)gvv << (4 * x);
            }
            A = An;
        }
        int e = 0; int cur = lt;
        for (int llv = 63; llv >= 0; --llv) {
            if (lane == llv) e = cur;
            unsigned long long Al = readlane_u64(A, llv);
            cur = (int)((Al >> (4 * cur)) & 15ULL);
        }
        unsigned long long pw = 0; int c2 = e;
#pragma unroll
        for (int r = 7; r >= 0; r--) {
            pw |= (unsigned long long)c2 << (8 * r);
            c2 = (int)((G[r] >> (4 * c2)) & 15ULL);
        }
        *(unsigned long long*)(pth + lane * 8) = pw;
    }
    __syncthreads();
    // ---- finalize: predict/label/correct for the block's 4 batches ----
    float cnt = 0.f;
#pragma unroll
    for (int q = 0; q < 8; q++) {
        int item = tid + q * 256;
        int bb = item >> 9;
        int t = item & (NS - 1);
        int b = b0 + bb;
        int idx = b * NS + t;
        int lab = label[idx];
        int p = (int)s_path[bb * NS + t];
        int pred = (lab > 0) ? p : 0;
        out[2 + idx] = (float)pred;
        out[2 + NROWS + idx] = (float)lab;
        cnt += (pred == lab) ? 1.f : 0.f;
    }
#pragma unroll
    for (int d = 1; d < 64; d <<= 1) cnt += __shfl_xor(cnt, d);
    if ((tid & 63) == 0) atomicAdd(out + 1, cnt);
}

extern "C" void kernel_launch(void* const* d_in, const int* in_sizes, int n_in,
                              void* d_out, int out_size, void* d_ws, size_t ws_size,
                              hipStream_t stream) {
    const float* hidden = (const float*)d_in[0];
    const int*   label  = (const int*)d_in[1];
    const int*   mask   = (const int*)d_in[2];
    const float* W      = (const float*)d_in[3];
    const float* bias   = (const float*)d_in[4];
    const float* startT = (const float*)d_in[5];
    const float* endT   = (const float*)d_in[6];
    const float* trans  = (const float*)d_in[7];
    float* out = (float*)d_out;

    float* em = (float*)d_ws;   // EMN floats

    k_gemm<<<8192, 256, 0, stream>>>(hidden, W, bias, em, out);
    k_dp<<<16, 256, 0, stream>>>(em, label, mask, startT, endT, trans, out);
}